// Round 9
// baseline (79.036 us; speedup 1.0000x reference)
//
#include <hip/hip_runtime.h>
#include <math.h>

#define BEAMS 16
#define TMAX  2048
#define HH    32
#define DD    128
#define NSP   24              // row-balanced t-splits
#define TSM   128             // max timesteps per split (span cap)
#define RCAP  16              // max staged rows per group
#define ROWF  292             // floats per staged row-pair: K[0..144), V[144..288), pad
#define GMAX  130             // max groups per split + sentinel

// ---------------------------------------------------------------------------
// Kernel 1: beam back-trace (suffix-composition scan) + dedup metadata +
// row-balanced split boundaries (prefix scan over per-t unique-row counts).
// ---------------------------------------------------------------------------
__global__ __launch_bounds__(1024)
void trace_kernel(const int* __restrict__ beam_idx,
                  const int* __restrict__ offp,
                  int* __restrict__ trace_tb,
                  unsigned long long* __restrict__ slot4_g,
                  int* __restrict__ rowstart_g,
                  int* __restrict__ rows_tu,
                  int* __restrict__ gt_g,
                  int* __restrict__ gr_g,
                  int* __restrict__ gct_g) {
    const int off = *offp;
    const int T   = off + 1;
    const int C   = 8;
    const int NC  = (off + C - 1) / C;     // <= 256

    __shared__ int S[2][256][BEAMS];                 // 32 KB (reused by scan)
    __shared__ unsigned short seen_s[TMAX];          // 4 KB
    __shared__ int ts_s[NSP + 1];

    const int tid = threadIdx.x;
    const int g   = tid >> 4;              // 64 groups
    const int j   = tid & 15;              // beam lane
    const int c0 = g, c1 = g + 64, c2 = g + 128, c3 = g + 192;

    // Phase A: per-chunk composed maps, 4 independent chains interleaved
    {
        int cur0 = j, cur1 = j, cur2 = j, cur3 = j;
        const int hi0 = (c0 < NC) ? min((c0 + 1) * C, off) : 0;
        const int hi1 = (c1 < NC) ? min((c1 + 1) * C, off) : 0;
        const int hi2 = (c2 < NC) ? min((c2 + 1) * C, off) : 0;
        const int hi3 = (c3 < NC) ? min((c3 + 1) * C, off) : 0;
        const int lo0 = c0 * C, lo1 = c1 * C, lo2 = c2 * C, lo3 = c3 * C;
        for (int i = 0; i < C; ++i) {
            const int ta = hi0 - 1 - i;
            if (c0 < NC && ta >= lo0) cur0 = beam_idx[ta * BEAMS + cur0];
            const int tb = hi1 - 1 - i;
            if (c1 < NC && tb >= lo1) cur1 = beam_idx[tb * BEAMS + cur1];
            const int tc = hi2 - 1 - i;
            if (c2 < NC && tc >= lo2) cur2 = beam_idx[tc * BEAMS + cur2];
            const int td = hi3 - 1 - i;
            if (c3 < NC && td >= lo3) cur3 = beam_idx[td * BEAMS + cur3];
        }
        if (c0 < NC) S[0][c0][j] = cur0;
        if (c1 < NC) S[0][c1][j] = cur1;
        if (c2 < NC) S[0][c2][j] = cur2;
        if (c3 < NC) S[0][c3][j] = cur3;
    }
    __syncthreads();

    // Phase B: suffix composition by doubling
    int rb = 0;
    for (int step = 1; step < NC; step <<= 1) {
        const int wb = rb ^ 1;
        for (int c = g; c < NC; c += 64) {
            int v;
            if (c + step < NC) v = S[rb][c][ S[rb][c + step][j] ];
            else               v = S[rb][c][j];
            S[wb][c][j] = v;
        }
        __syncthreads();
        rb = wb;
    }

    // Phase C: re-walk chunks seeded with the next chunk's suffix map
    {
        int cur0 = (c0 + 1 < NC) ? S[rb][c0 + 1][j] : j;
        int cur1 = (c1 + 1 < NC) ? S[rb][c1 + 1][j] : j;
        int cur2 = (c2 + 1 < NC) ? S[rb][c2 + 1][j] : j;
        int cur3 = (c3 + 1 < NC) ? S[rb][c3 + 1][j] : j;
        const int hi0 = (c0 < NC) ? min((c0 + 1) * C, off) : 0;
        const int hi1 = (c1 < NC) ? min((c1 + 1) * C, off) : 0;
        const int hi2 = (c2 < NC) ? min((c2 + 1) * C, off) : 0;
        const int hi3 = (c3 < NC) ? min((c3 + 1) * C, off) : 0;
        const int lo0 = c0 * C, lo1 = c1 * C, lo2 = c2 * C, lo3 = c3 * C;
        for (int i = 0; i < C; ++i) {
            const int ta = hi0 - 1 - i;
            if (c0 < NC && ta >= lo0) {
                cur0 = beam_idx[ta * BEAMS + cur0];
                trace_tb[ta * BEAMS + j] = cur0;
            }
            const int tb = hi1 - 1 - i;
            if (c1 < NC && tb >= lo1) {
                cur1 = beam_idx[tb * BEAMS + cur1];
                trace_tb[tb * BEAMS + j] = cur1;
            }
            const int tc = hi2 - 1 - i;
            if (c2 < NC && tc >= lo2) {
                cur2 = beam_idx[tc * BEAMS + cur2];
                trace_tb[tc * BEAMS + j] = cur2;
            }
            const int td = hi3 - 1 - i;
            if (c3 < NC && td >= lo3) {
                cur3 = beam_idx[td * BEAMS + cur3];
                trace_tb[td * BEAMS + j] = cur3;
            }
        }
    }
    __syncthreads();   // drains vmcnt: trace_tb stores visible to this block

    // ---- dedup: per t, seen-mask + 4-bit slots (rank of set bit) ----
    for (int t = tid; t < T; t += 1024) {
        if (t == off) {
            seen_s[t]  = 0xFFFFu;
            slot4_g[t] = 0xFEDCBA9876543210ull;   // slot_b = b
        } else {
            unsigned seen = 0;
            int us[16];
            #pragma unroll
            for (int b2 = 0; b2 < 16; ++b2) {
                us[b2] = trace_tb[t * BEAMS + b2];
                seen |= 1u << us[b2];
            }
            unsigned long long s4 = 0;
            #pragma unroll
            for (int b2 = 0; b2 < 16; ++b2) {
                const unsigned long long sl =
                    (unsigned long long)__popc(seen & ((1u << us[b2]) - 1u));
                s4 |= sl << (4 * b2);
            }
            seen_s[t]  = (unsigned short)seen;
            slot4_g[t] = s4;
        }
    }
    __syncthreads();

    // ---- inclusive prefix scan of n_t (reuse S as two 2048-int buffers) ----
    int* scanA = &S[0][0][0];
    int* scanB = &S[1][0][0];
    for (int t = tid; t < TMAX; t += 1024)
        scanA[t] = (t < T) ? __popc((unsigned)seen_s[t]) : 0;
    __syncthreads();
    int* src = scanA; int* dst = scanB;
    for (int step = 1; step < TMAX; step <<= 1) {
        for (int i = tid; i < TMAX; i += 1024)
            dst[i] = src[i] + ((i >= step) ? src[i - step] : 0);
        __syncthreads();
        int* tmp = src; src = dst; dst = tmp;
    }
    // src = inclusive prefix; excl[t] = (t>0 ? src[t-1] : 0)

    // ---- row-balanced boundaries with span cap (wave 0 only) ----
    if (tid < 64) {
        const int total = src[T - 1];
        const int rps   = (total + NSP - 1) / NSP;
        const int s     = tid;
        int fwd;
        if (s == 0)        fwd = 0;
        else if (s >= NSP) fwd = T;
        else {
            const int target = s * rps;
            int lo = 0, hi = T;
            while (lo < hi) {
                const int mid = (lo + hi) >> 1;
                const int ex  = (mid > 0) ? src[mid - 1] : 0;
                if (ex >= target) hi = mid; else lo = mid + 1;
            }
            fwd = lo;
        }
        // min-plus prefix (span cap): ts_cap[s] = s*TSM + min_{j<=s}(fwd[j]-j*TSM)
        int a = (s <= NSP) ? (fwd - s * TSM) : 0x3FFFFFFF;
        #pragma unroll
        for (int o = 1; o < 64; o <<= 1) {
            const int other = __shfl_up(a, o, 64);
            if (tid >= o) a = min(a, other);
        }
        if (s <= NSP) {
            int ts = s * TSM + a;
            ts = max(ts, T - (NSP - s) * TSM);   // backward feasibility
            ts = max(ts, 0);
            ts = min(ts, T);
            ts_s[s] = ts;
        }
    }
    __syncthreads();

    // ---- grouping + row-list emission: one lane per split ----
    if (tid < NSP) {
        const int s   = tid;
        const int ts0 = ts_s[s];
        const int ts1 = ts_s[s + 1];
        int cum = 0, gi = 0, gcum = 0;
        gt_g[s * GMAX + 0] = ts0;
        gr_g[s * GMAX + 0] = 0;
        for (int t = ts0; t < ts1; ++t) {
            const unsigned seen = seen_s[t];
            const int n = __popc(seen);
            if (gcum + n > RCAP) {
                ++gi;
                gt_g[s * GMAX + gi] = t;
                gr_g[s * GMAX + gi] = cum;
                gcum = 0;
            }
            rowstart_g[t] = cum;
            if (t == off) {
                for (int k = 0; k < 16; ++k)
                    rows_tu[s * 2048 + cum + k] = t * 32 + k;
            } else {
                int k = 0;
                for (unsigned m = seen; m; m &= m - 1) {
                    rows_tu[s * 2048 + cum + k] = t * 32 + (__ffs(m) - 1);
                    ++k;
                }
            }
            cum  += n;
            gcum += n;
        }
        ++gi;
        gt_g[s * GMAX + gi] = ts1;
        gr_g[s * GMAX + gi] = cum;
        gct_g[s] = gi;    // groups 0..gi-1; entry gi is the sentinel
    }
}

// ---------------------------------------------------------------------------
// Kernel 2: flash-decode split, unique-row LDS staging, DOUBLE-BUFFERED.
// Block = (h, balanced split). Per group g: {ds_write regs->buf[g&1];
// issue group g+1 global loads->regs; barrier; compute buf[g&1]}.
// One barrier per group is sufficient: a write to buf X at iter g+2 is
// ordered after barrier(g+1), which every wave reaches only after its
// compute(g) of buf X.  3 blocks/CU (48.5 KB LDS, launch_bounds(256,3)).
// ---------------------------------------------------------------------------
__global__ __launch_bounds__(256, 3)
void attn_split_kernel(const float* __restrict__ q,
                       const float* __restrict__ knew,
                       const float* __restrict__ vnew,
                       const float* __restrict__ kc,
                       const float* __restrict__ vc,
                       const float* __restrict__ mask,
                       const unsigned long long* __restrict__ slot4_g,
                       const int* __restrict__ rowstart_g,
                       const int* __restrict__ rows_tu,
                       const int* __restrict__ gt_g,
                       const int* __restrict__ gr_g,
                       const int* __restrict__ gct_g,
                       const int* __restrict__ offp,
                       float* __restrict__ pl,
                       float* __restrict__ po) {
    const int off = *offp;
    const int T   = off + 1;
    const int h   = blockIdx.x / NSP;
    const int s   = blockIdx.x - h * NSP;

    const int gct = gct_g[s];
    const int ts0 = gt_g[s * GMAX + 0];
    const int ts1 = gt_g[s * GMAX + gct];
    const int nts = ts1 - ts0;                     // <= TSM

    __shared__ float rowbuf[2 * RCAP * ROWF];      // 37,376 B (reused as oacc)
    __shared__ float mask_s[16][TSM + 2];          //  8,320 B
    __shared__ unsigned long long slot4_s[TSM];    //  1,024 B
    __shared__ int   rbase_s[TSM];                 //    512 B
    __shared__ int   gtl[GMAX], grl[GMAX];         //  1,040 B
    __shared__ float ls[4][16];                    //    256 B

    const int tid  = threadIdx.x;
    const int w    = tid >> 6;                     // wave 0..3
    const int lane = tid & 63;
    const int b    = lane & 15;                    // beam
    const int dg   = lane >> 4;                    // 0..3
    const int qd   = (dg + b) & 3;                 // rotated quarter
    const int bh   = b * HH + h;

    // ---- stage per-split metadata ----
    for (int i = tid; i < 16 * TSM; i += 256) {
        const int bb = i >> 7, tt = i & (TSM - 1);
        mask_s[bb][tt] = (tt < nts) ? mask[(size_t)bb * T + ts0 + tt] : 0.f;
    }
    for (int i = tid; i < nts; i += 256) {
        slot4_s[i] = slot4_g[ts0 + i];
        rbase_s[i] = rowstart_g[ts0 + i];
    }
    for (int i = tid; i <= gct; i += 256) {
        gtl[i] = gt_g[s * GMAX + i];
        grl[i] = gr_g[s * GMAX + i];
    }

    const float inv_scale = 0.08838834764831843f;  // 1/sqrt(128)
    float4 qr[8];
    {
        const float* qp = q + (size_t)bh * DD + qd * 32;
        #pragma unroll
        for (int jj = 0; jj < 8; ++jj) {
            float4 t4 = *(const float4*)(qp + jj * 4);
            t4.x *= inv_scale; t4.y *= inv_scale; t4.z *= inv_scale; t4.w *= inv_scale;
            qr[jj] = t4;
        }
    }

    float4 orf[8];
    #pragma unroll
    for (int jj = 0; jj < 8; ++jj) orf[jj] = make_float4(0.f, 0.f, 0.f, 0.f);
    float l_acc = 0.f;

    __syncthreads();   // metadata staged

    // ---- staging lane mapping ----
    const int c     = tid & 15;
    const int myrow = tid >> 4;                    // one row per thread (RCAP=16)
    const int dstq  = (c >> 2) * 36 + (c & 3) * 8; // quarter-padded dest
    float4 ka, kb, va, vb;
    int have = 0;

#define LOADG(GI)                                                            \
    {                                                                        \
        const int r0_ = grl[GI];                                             \
        const int nr_ = grl[(GI) + 1] - r0_;                                 \
        have = (myrow < nr_);                                                \
        if (have) {                                                          \
            const int tu = rows_tu[s * 2048 + r0_ + myrow];                  \
            const int t_ = tu >> 5;                                          \
            const int u_ = tu & 31;                                          \
            const float *ksrc, *vsrc;                                        \
            if (t_ < off) {                                                  \
                const size_t ro = ((size_t)(t_ * BEAMS + u_) * HH + h) * DD; \
                ksrc = kc + ro; vsrc = vc + ro;                              \
            } else {                                                         \
                const size_t ro = ((size_t)u_ * HH + h) * DD;                \
                ksrc = knew + ro; vsrc = vnew + ro;                          \
            }                                                                \
            ka = *(const float4*)(ksrc + c * 8);                             \
            kb = *(const float4*)(ksrc + c * 8 + 4);                         \
            va = *(const float4*)(vsrc + c * 8);                             \
            vb = *(const float4*)(vsrc + c * 8 + 4);                         \
        }                                                                    \
    }

    if (gct > 0) LOADG(0);

    for (int gi = 0; gi < gct; ++gi) {
        float* buf = rowbuf + (gi & 1) * (RCAP * ROWF);
        if (have) {
            float* dst = buf + myrow * ROWF;
            *(float4*)(dst + dstq)           = ka;
            *(float4*)(dst + dstq + 4)       = kb;
            *(float4*)(dst + 144 + dstq)     = va;
            *(float4*)(dst + 144 + dstq + 4) = vb;
        }
        if (gi + 1 < gct) LOADG(gi + 1);           // prefetch next group
        __syncthreads();                           // buf ready

        const int t_lo = gtl[gi], t_hi = gtl[gi + 1];
        const int r0g  = grl[gi];
        for (int t = t_lo + w; t < t_hi; t += 4) {
            const int tt = t - ts0;
            const unsigned long long s4 = slot4_s[tt];
            const int slot = (int)((s4 >> (4 * b)) & 15);
            const int row  = (rbase_s[tt] - r0g) + slot;
            const float* kr = buf + row * ROWF + qd * 36;
            float sc = 0.f;
            #pragma unroll
            for (int jj = 0; jj < 8; ++jj) {
                const float4 kv = *(const float4*)(kr + jj * 4);
                sc = fmaf(qr[jj].x, kv.x, sc);
                sc = fmaf(qr[jj].y, kv.y, sc);
                sc = fmaf(qr[jj].z, kv.z, sc);
                sc = fmaf(qr[jj].w, kv.w, sc);
            }
            sc += __shfl_xor(sc, 16, 64);
            sc += __shfl_xor(sc, 32, 64);
            const float p = __expf(sc + mask_s[b][tt]);
            l_acc += p;                            // identical across dg lanes
            const float* vr = kr + 144;
            #pragma unroll
            for (int jj = 0; jj < 8; ++jj) {
                const float4 vv = *(const float4*)(vr + jj * 4);
                orf[jj].x = fmaf(p, vv.x, orf[jj].x);
                orf[jj].y = fmaf(p, vv.y, orf[jj].y);
                orf[jj].z = fmaf(p, vv.z, orf[jj].z);
                orf[jj].w = fmaf(p, vv.w, orf[jj].w);
            }
        }
    }
#undef LOADG
    __syncthreads();   // all compute done before rowbuf reuse

    // ---- cross-wave merge: reuse rowbuf as oacc[w][16][132] ----
    {
        float* oa = rowbuf + (w * 16 + b) * 132 + qd * 32;
        #pragma unroll
        for (int jj = 0; jj < 8; ++jj) *(float4*)(oa + jj * 4) = orf[jj];
        if (dg == 0) ls[w][b] = l_acc;
    }
    __syncthreads();
    {
        const int b2 = tid >> 4;
        const int cc = tid & 15;
        float* pop = po + ((size_t)(b2 * HH + h) * NSP + s) * DD;
        #pragma unroll
        for (int jj = 0; jj < 8; ++jj) {
            const int d = cc * 8 + jj;
            pop[d] = rowbuf[(0 * 16 + b2) * 132 + d]
                   + rowbuf[(1 * 16 + b2) * 132 + d]
                   + rowbuf[(2 * 16 + b2) * 132 + d]
                   + rowbuf[(3 * 16 + b2) * 132 + d];
        }
        if (cc == 0)
            pl[(size_t)(b2 * HH + h) * NSP + s] =
                ls[0][b2] + ls[1][b2] + ls[2][b2] + ls[3][b2];
    }
}

// ---------------------------------------------------------------------------
// Kernel 3: merge the NSP partials per (b,h) — plain sum + normalize.
// ---------------------------------------------------------------------------
__global__ __launch_bounds__(128)
void attn_reduce_kernel(const float* __restrict__ pl,
                        const float* __restrict__ po,
                        float* __restrict__ out) {
    const int bh = blockIdx.x;
    const int d  = threadIdx.x;
    float l = 0.f, o = 0.f;
    #pragma unroll 8
    for (int s = 0; s < NSP; ++s) {
        l += pl[(size_t)bh * NSP + s];
        o += po[((size_t)bh * NSP + s) * DD + d];
    }
    out[(size_t)bh * DD + d] = o / l;
}

// ---------------------------------------------------------------------------
extern "C" void kernel_launch(void* const* d_in, const int* in_sizes, int n_in,
                              void* d_out, int out_size, void* d_ws, size_t ws_size,
                              hipStream_t stream) {
    const float* q    = (const float*)d_in[0];
    const float* knew = (const float*)d_in[1];
    const float* vnew = (const float*)d_in[2];
    const float* kc   = (const float*)d_in[3];
    const float* vc   = (const float*)d_in[4];
    const int*   bidx = (const int*)d_in[5];
    const float* mask = (const float*)d_in[6];
    const int*   offp = (const int*)d_in[7];

    char* ws = (char*)d_ws;
    int*                trace_tb = (int*)(ws);                          // 131072
    unsigned long long* slot4    = (unsigned long long*)(ws + 131072);  // 16384
    int*                rowstart = (int*)(ws + 147456);                 // 8192
    int*                rows_tu  = (int*)(ws + 155648);                 // 196608
    int*                gt_g     = (int*)(ws + 352256);                 // 12480
    int*                gr_g     = (int*)(ws + 364736);                 // 12480
    int*                gct_g    = (int*)(ws + 377216);                 // 128
    float*              pl       = (float*)(ws + 377344);               // 49152
    float*              po       = (float*)(ws + 426496);               // 393216

    hipLaunchKernelGGL(trace_kernel, dim3(1), dim3(1024), 0, stream,
                       bidx, offp, trace_tb, slot4, rowstart, rows_tu,
                       gt_g, gr_g, gct_g);
    hipLaunchKernelGGL(attn_split_kernel, dim3(HH * NSP), dim3(256), 0, stream,
                       q, knew, vnew, kc, vc, mask,
                       slot4, rowstart, rows_tu, gt_g, gr_g, gct_g, offp,
                       pl, po);
    hipLaunchKernelGGL(attn_reduce_kernel, dim3(BEAMS * HH), dim3(128), 0, stream,
                       pl, po, (float*)d_out);
}

// Round 10
// 67.833 us; speedup vs baseline: 1.1652x; 1.1652x over previous
//
#include <hip/hip_runtime.h>
#include <math.h>

#define BEAMS 16
#define TMAX  2048
#define HH    32
#define DD    128
#define NSP   24              // row-balanced t-splits
#define TSM   128             // max timesteps per split (span cap)
#define KLD   136             // staged row stride in bf16 elems (128 + 8 pad; 272B, 16B-aligned)
#define WLD   40              // Wt row stride (bf16)

typedef float          f32x4 __attribute__((ext_vector_type(4)));
typedef short          s16x8 __attribute__((ext_vector_type(8)));
typedef unsigned short u16x8 __attribute__((ext_vector_type(8)));

__device__ __forceinline__ unsigned short f2bf(float f) {
    unsigned x = __float_as_uint(f);
    return (unsigned short)((x + 0x7FFFu + ((x >> 16) & 1u)) >> 16);   // RNE
}

// assumed A/B k-permutation pi(g,j); any mismatch vs HW cancels (used on BOTH operands)
__device__ __forceinline__ int kofs(int g, int j) {
    return (j < 4) ? (g * 4 + j) : (16 + g * 4 + (j - 4));
}

// ---------------------------------------------------------------------------
// Kernel 1: beam back-trace + dedup metadata + row-balanced split boundaries.
// ---------------------------------------------------------------------------
__global__ __launch_bounds__(1024)
void trace_kernel(const int* __restrict__ beam_idx,
                  const int* __restrict__ offp,
                  int* __restrict__ trace_tb,
                  unsigned long long* __restrict__ slot4_g,
                  int* __restrict__ rowstart_g,
                  int* __restrict__ rows_tu,
                  int* __restrict__ ts_g,
                  int* __restrict__ ucnt_g) {
    const int off = *offp;
    const int T   = off + 1;
    const int C   = 8;
    const int NC  = (off + C - 1) / C;     // <= 256

    __shared__ int S[2][256][BEAMS];                 // 32 KB (reused by scan)
    __shared__ unsigned short seen_s[TMAX];          // 4 KB
    __shared__ int ts_s[NSP + 1];

    const int tid = threadIdx.x;
    const int g   = tid >> 4;              // 64 groups
    const int j   = tid & 15;              // beam lane
    const int c0 = g, c1 = g + 64, c2 = g + 128, c3 = g + 192;

    // Phase A: per-chunk composed maps, 4 independent chains interleaved
    {
        int cur0 = j, cur1 = j, cur2 = j, cur3 = j;
        const int hi0 = (c0 < NC) ? min((c0 + 1) * C, off) : 0;
        const int hi1 = (c1 < NC) ? min((c1 + 1) * C, off) : 0;
        const int hi2 = (c2 < NC) ? min((c2 + 1) * C, off) : 0;
        const int hi3 = (c3 < NC) ? min((c3 + 1) * C, off) : 0;
        const int lo0 = c0 * C, lo1 = c1 * C, lo2 = c2 * C, lo3 = c3 * C;
        for (int i = 0; i < C; ++i) {
            const int ta = hi0 - 1 - i;
            if (c0 < NC && ta >= lo0) cur0 = beam_idx[ta * BEAMS + cur0];
            const int tb = hi1 - 1 - i;
            if (c1 < NC && tb >= lo1) cur1 = beam_idx[tb * BEAMS + cur1];
            const int tc = hi2 - 1 - i;
            if (c2 < NC && tc >= lo2) cur2 = beam_idx[tc * BEAMS + cur2];
            const int td = hi3 - 1 - i;
            if (c3 < NC && td >= lo3) cur3 = beam_idx[td * BEAMS + cur3];
        }
        if (c0 < NC) S[0][c0][j] = cur0;
        if (c1 < NC) S[0][c1][j] = cur1;
        if (c2 < NC) S[0][c2][j] = cur2;
        if (c3 < NC) S[0][c3][j] = cur3;
    }
    __syncthreads();

    // Phase B: suffix composition by doubling
    int rb = 0;
    for (int step = 1; step < NC; step <<= 1) {
        const int wb = rb ^ 1;
        for (int c = g; c < NC; c += 64) {
            int v;
            if (c + step < NC) v = S[rb][c][ S[rb][c + step][j] ];
            else               v = S[rb][c][j];
            S[wb][c][j] = v;
        }
        __syncthreads();
        rb = wb;
    }

    // Phase C: re-walk chunks seeded with the next chunk's suffix map
    {
        int cur0 = (c0 + 1 < NC) ? S[rb][c0 + 1][j] : j;
        int cur1 = (c1 + 1 < NC) ? S[rb][c1 + 1][j] : j;
        int cur2 = (c2 + 1 < NC) ? S[rb][c2 + 1][j] : j;
        int cur3 = (c3 + 1 < NC) ? S[rb][c3 + 1][j] : j;
        const int hi0 = (c0 < NC) ? min((c0 + 1) * C, off) : 0;
        const int hi1 = (c1 < NC) ? min((c1 + 1) * C, off) : 0;
        const int hi2 = (c2 < NC) ? min((c2 + 1) * C, off) : 0;
        const int hi3 = (c3 < NC) ? min((c3 + 1) * C, off) : 0;
        const int lo0 = c0 * C, lo1 = c1 * C, lo2 = c2 * C, lo3 = c3 * C;
        for (int i = 0; i < C; ++i) {
            const int ta = hi0 - 1 - i;
            if (c0 < NC && ta >= lo0) {
                cur0 = beam_idx[ta * BEAMS + cur0];
                trace_tb[ta * BEAMS + j] = cur0;
            }
            const int tb = hi1 - 1 - i;
            if (c1 < NC && tb >= lo1) {
                cur1 = beam_idx[tb * BEAMS + cur1];
                trace_tb[tb * BEAMS + j] = cur1;
            }
            const int tc = hi2 - 1 - i;
            if (c2 < NC && tc >= lo2) {
                cur2 = beam_idx[tc * BEAMS + cur2];
                trace_tb[tc * BEAMS + j] = cur2;
            }
            const int td = hi3 - 1 - i;
            if (c3 < NC && td >= lo3) {
                cur3 = beam_idx[td * BEAMS + cur3];
                trace_tb[td * BEAMS + j] = cur3;
            }
        }
    }
    __syncthreads();

    // ---- dedup: per t, seen-mask + 4-bit slots (rank of set bit) ----
    for (int t = tid; t < T; t += 1024) {
        if (t == off) {
            seen_s[t]  = 0xFFFFu;
            slot4_g[t] = 0xFEDCBA9876543210ull;   // slot_b = b
        } else {
            unsigned seen = 0;
            int us[16];
            #pragma unroll
            for (int b2 = 0; b2 < 16; ++b2) {
                us[b2] = trace_tb[t * BEAMS + b2];
                seen |= 1u << us[b2];
            }
            unsigned long long s4 = 0;
            #pragma unroll
            for (int b2 = 0; b2 < 16; ++b2) {
                const unsigned long long sl =
                    (unsigned long long)__popc(seen & ((1u << us[b2]) - 1u));
                s4 |= sl << (4 * b2);
            }
            seen_s[t]  = (unsigned short)seen;
            slot4_g[t] = s4;
        }
    }
    __syncthreads();

    // ---- inclusive prefix scan of n_t (reuse S as two 2048-int buffers) ----
    int* scanA = &S[0][0][0];
    int* scanB = &S[1][0][0];
    for (int t = tid; t < TMAX; t += 1024)
        scanA[t] = (t < T) ? __popc((unsigned)seen_s[t]) : 0;
    __syncthreads();
    int* src = scanA; int* dst = scanB;
    for (int step = 1; step < TMAX; step <<= 1) {
        for (int i = tid; i < TMAX; i += 1024)
            dst[i] = src[i] + ((i >= step) ? src[i - step] : 0);
        __syncthreads();
        int* tmp = src; src = dst; dst = tmp;
    }

    // ---- row-balanced boundaries with span cap (wave 0 only) ----
    if (tid < 64) {
        const int total = src[T - 1];
        const int rps   = (total + NSP - 1) / NSP;
        const int s     = tid;
        int fwd;
        if (s == 0)        fwd = 0;
        else if (s >= NSP) fwd = T;
        else {
            const int target = s * rps;
            int lo = 0, hi = T;
            while (lo < hi) {
                const int mid = (lo + hi) >> 1;
                const int ex  = (mid > 0) ? src[mid - 1] : 0;
                if (ex >= target) hi = mid; else lo = mid + 1;
            }
            fwd = lo;
        }
        int a = (s <= NSP) ? (fwd - s * TSM) : 0x3FFFFFFF;
        #pragma unroll
        for (int o = 1; o < 64; o <<= 1) {
            const int other = __shfl_up(a, o, 64);
            if (tid >= o) a = min(a, other);
        }
        if (s <= NSP) {
            int ts = s * TSM + a;
            ts = max(ts, T - (NSP - s) * TSM);
            ts = max(ts, 0);
            ts = min(ts, T);
            ts_s[s] = ts;
        }
    }
    __syncthreads();

    // ---- row-list emission: one lane per split ----
    if (tid < NSP) {
        const int s   = tid;
        const int ts0 = ts_s[s];
        const int ts1 = ts_s[s + 1];
        int cum = 0;
        for (int t = ts0; t < ts1; ++t) {
            const unsigned seen = seen_s[t];
            rowstart_g[t] = cum;
            if (t == off) {
                for (int k = 0; k < 16; ++k)
                    rows_tu[s * 2048 + cum + k] = t * 32 + k;
                cum += 16;
            } else {
                int k = 0;
                for (unsigned m = seen; m; m &= m - 1) {
                    rows_tu[s * 2048 + cum + k] = t * 32 + (__ffs(m) - 1);
                    ++k;
                }
                cum += k;
            }
        }
        ucnt_g[s] = cum;
    }
    if (tid <= NSP) ts_g[tid] = ts_s[tid];
}

// ---------------------------------------------------------------------------
// Kernel 2: MFMA flash-decode over unique rows.
// Block = (h, balanced split). Per 32-row group:
//   stage K/V bf16 (dbuf) -> QK^T via mfma_f32_16x16x32_bf16 (waves 0,1) ->
//   W-fill (exp + slot-match select, verified C/D layout) -> Wt in LDS ->
//   PV via mfma, waves split the 8 d-tiles. The unknown A/B k-permutation
//   cancels: both operands of each contraction are placed with the same
//   assumed kofs().
// ---------------------------------------------------------------------------
__global__ __launch_bounds__(256, 3)
void attn_split_kernel(const float* __restrict__ q,
                       const float* __restrict__ knew,
                       const float* __restrict__ vnew,
                       const float* __restrict__ kc,
                       const float* __restrict__ vc,
                       const float* __restrict__ mask,
                       const unsigned long long* __restrict__ slot4_g,
                       const int* __restrict__ rowstart_g,
                       const int* __restrict__ rows_tu,
                       const int* __restrict__ ts_g,
                       const int* __restrict__ ucnt_g,
                       const int* __restrict__ offp,
                       float* __restrict__ pl,
                       float* __restrict__ po) {
    const int off = *offp;
    const int T   = off + 1;
    const int h   = blockIdx.x / NSP;
    const int s   = blockIdx.x - h * NSP;
    const int ts0 = ts_g[s], ts1 = ts_g[s + 1];
    const int nts = ts1 - ts0;
    const int U   = ucnt_g[s];
    const int G   = (U + 31) >> 5;

    __shared__ unsigned short Kb[2][32][KLD];      // 17,408 B
    __shared__ unsigned short Vb[2][32][KLD];      // 17,408 B
    __shared__ unsigned short Wt[16][WLD];         //  1,280 B
    __shared__ float mask_s[16][TSM];              //  8,192 B
    __shared__ unsigned long long slot4_s[TSM];    //  1,024 B
    __shared__ int   rbase_s[TSM];                 //    512 B
    __shared__ float ls[2][16];                    //    128 B

    const int tid = threadIdx.x;
    const int w   = tid >> 6;                      // wave 0..3
    const int l   = tid & 63;
    const int n16 = l & 15;
    const int g4  = l >> 4;

    // ---- metadata staging ----
    for (int i = tid; i < 16 * TSM; i += 256) {
        const int bb = i >> 7, tt = i & (TSM - 1);
        mask_s[bb][tt] = (tt < nts) ? mask[(size_t)bb * T + ts0 + tt] : 0.f;
    }
    for (int i = tid; i < nts; i += 256) {
        slot4_s[i] = slot4_g[ts0 + i];
        rbase_s[i] = rowstart_g[ts0 + i];
    }

    // ---- Q B-fragments (bf16, pre-scaled), one per 32-d chunk ----
    const float inv_scale = 0.08838834764831843f;  // 1/sqrt(128)
    s16x8 qf[4];
    {
        const float* qp = q + ((size_t)(n16 * HH + h)) * DD;
        #pragma unroll
        for (int c = 0; c < 4; ++c) {
            const int base = 32 * c + g4 * 4;
            const float4 lo = *(const float4*)(qp + base);
            const float4 hi = *(const float4*)(qp + base + 16);
            qf[c][0] = (short)f2bf(lo.x * inv_scale);
            qf[c][1] = (short)f2bf(lo.y * inv_scale);
            qf[c][2] = (short)f2bf(lo.z * inv_scale);
            qf[c][3] = (short)f2bf(lo.w * inv_scale);
            qf[c][4] = (short)f2bf(hi.x * inv_scale);
            qf[c][5] = (short)f2bf(hi.y * inv_scale);
            qf[c][6] = (short)f2bf(hi.z * inv_scale);
            qf[c][7] = (short)f2bf(hi.w * inv_scale);
        }
    }

    // staging roles: thread handles rows r1 and r1+16 of each 32-row group
    const int r1 = tid >> 4;
    const int cc = tid & 15;
    float4 sk1a, sk1b, sv1a, sv1b, sk2a, sk2b, sv2a, sv2b;

#define LOADR(UU, KA, KB, VA, VB)                                            \
    {                                                                        \
        const int uu = (UU);                                                 \
        const int tu = (uu < U) ? rows_tu[s * 2048 + uu] : 0;                \
        const int t_ = tu >> 5, u_ = tu & 31;                                \
        const float *ks, *vs;                                                \
        if (t_ < off) {                                                      \
            const size_t ro = ((size_t)(t_ * BEAMS + u_) * HH + h) * DD;     \
            ks = kc + ro; vs = vc + ro;                                      \
        } else {                                                             \
            const size_t ro = ((size_t)u_ * HH + h) * DD;                    \
            ks = knew + ro; vs = vnew + ro;                                  \
        }                                                                    \
        KA = *(const float4*)(ks + cc * 8);                                  \
        KB = *(const float4*)(ks + cc * 8 + 4);                              \
        VA = *(const float4*)(vs + cc * 8);                                  \
        VB = *(const float4*)(vs + cc * 8 + 4);                              \
    }

#define PACK8(DST, A, B)                                                     \
    {                                                                        \
        u16x8 p_;                                                            \
        p_[0] = f2bf(A.x); p_[1] = f2bf(A.y); p_[2] = f2bf(A.z);             \
        p_[3] = f2bf(A.w); p_[4] = f2bf(B.x); p_[5] = f2bf(B.y);             \
        p_[6] = f2bf(B.z); p_[7] = f2bf(B.w);                                \
        *(u16x8*)(DST) = p_;                                                 \
    }

    f32x4 accO0 = {0.f, 0.f, 0.f, 0.f};
    f32x4 accO1 = {0.f, 0.f, 0.f, 0.f};
    float l_acc = 0.f;

    __syncthreads();   // metadata staged

    if (G > 0) { LOADR(0 * 32 + r1, sk1a, sk1b, sv1a, sv1b)
                 LOADR(0 * 32 + r1 + 16, sk2a, sk2b, sv2a, sv2b) }

    for (int g = 0; g < G; ++g) {
        const int buf = g & 1;
        // ds_write staged rows (bf16)
        PACK8(&Kb[buf][r1][cc * 8],      sk1a, sk1b)
        PACK8(&Vb[buf][r1][cc * 8],      sv1a, sv1b)
        PACK8(&Kb[buf][r1 + 16][cc * 8], sk2a, sk2b)
        PACK8(&Vb[buf][r1 + 16][cc * 8], sv2a, sv2b)
        if (g + 1 < G) {
            LOADR((g + 1) * 32 + r1, sk1a, sk1b, sv1a, sv1b)
            LOADR((g + 1) * 32 + r1 + 16, sk2a, sk2b, sv2a, sv2b)
        }
        __syncthreads();   // K/V/metadata for group g staged

        // ---- QK^T + W-fill: waves 0,1 (tile T = w: u-local w*16..+16) ----
        if (w < 2) {
            f32x4 acc = {0.f, 0.f, 0.f, 0.f};
            const unsigned short* krow = &Kb[buf][w * 16 + n16][0];
            #pragma unroll
            for (int c = 0; c < 4; ++c) {
                const unsigned short* ka = krow + 32 * c + g4 * 4;
                union { unsigned long long qw[2]; s16x8 v; } ua;
                ua.qw[0] = *(const unsigned long long*)(ka);
                ua.qw[1] = *(const unsigned long long*)(ka + 16);
                acc = __builtin_amdgcn_mfma_f32_16x16x32_bf16(ua.v, qf[c], acc, 0, 0, 0);
            }
            // W-fill (C/D layout: col=lane&15=b, row=(lane>>4)*4+r=u-local)
            unsigned short wout[4];
            #pragma unroll
            for (int r = 0; r < 4; ++r) {
                const int u_loc = g * 32 + w * 16 + g4 * 4 + r;
                const bool valid = (u_loc < U);
                const int tu = valid ? rows_tu[s * 2048 + u_loc] : 0;
                const int t_ = tu >> 5;
                const int tt = (t_ - ts0) & (TSM - 1);
                const unsigned long long s4 = slot4_s[tt];
                const int myslot = (int)((s4 >> (4 * n16)) & 15);
                const int expsl  = u_loc - rbase_s[tt];
                const bool match = valid && (myslot == expsl);
                const float sc = acc[r] + mask_s[n16][tt];
                const float wv = match ? __expf(sc) : 0.f;
                l_acc += wv;
                wout[r] = f2bf(wv);
            }
            const int wc = w * 16 + g4 * 4;
            *(unsigned*)&Wt[n16][wc]     = (unsigned)wout[0] | ((unsigned)wout[1] << 16);
            *(unsigned*)&Wt[n16][wc + 2] = (unsigned)wout[2] | ((unsigned)wout[3] << 16);
        }
        __syncthreads();   // Wt ready

        // ---- PV: O[b][d] += W^T . V ; wave w owns d-tiles 2w, 2w+1 ----
        {
            union { unsigned long long qw[2]; s16x8 v; } uw;
            uw.qw[0] = *(const unsigned long long*)(&Wt[n16][g4 * 4]);
            uw.qw[1] = *(const unsigned long long*)(&Wt[n16][16 + g4 * 4]);
            s16x8 bf0, bf1;
            const int d0 = (w * 2) * 16 + n16;
            const int d1 = (w * 2 + 1) * 16 + n16;
            #pragma unroll
            for (int jj = 0; jj < 8; ++jj) {
                const int k = kofs(g4, jj);
                bf0[jj] = (short)Vb[buf][k][d0];
                bf1[jj] = (short)Vb[buf][k][d1];
            }
            accO0 = __builtin_amdgcn_mfma_f32_16x16x32_bf16(uw.v, bf0, accO0, 0, 0, 0);
            accO1 = __builtin_amdgcn_mfma_f32_16x16x32_bf16(uw.v, bf1, accO1, 0, 0, 0);
        }
        __syncthreads();   // PV done before next group's stores
    }
#undef LOADR
#undef PACK8

    // ---- l reduction (waves 0,1 hold partials per b=n16 across g4) ----
    if (w < 2) {
        l_acc += __shfl_xor(l_acc, 16, 64);
        l_acc += __shfl_xor(l_acc, 32, 64);
        if (l < 16) ls[w][n16] = l_acc;
    }
    __syncthreads();
    if (tid < 16)
        pl[((size_t)tid * HH + h) * NSP + s] = ls[0][tid] + ls[1][tid];

    // ---- O write (C/D layout: col=n16=d-local, row=(g4*4+r)=b) ----
    #pragma unroll
    for (int r = 0; r < 4; ++r) {
        const int b = g4 * 4 + r;
        const size_t base = ((size_t)(b * HH + h) * NSP + s) * DD;
        po[base + (w * 2) * 16 + n16]     = accO0[r];
        po[base + (w * 2 + 1) * 16 + n16] = accO1[r];
    }
}

// ---------------------------------------------------------------------------
// Kernel 3: merge the NSP partials per (b,h) — plain sum + normalize.
// ---------------------------------------------------------------------------
__global__ __launch_bounds__(128)
void attn_reduce_kernel(const float* __restrict__ pl,
                        const float* __restrict__ po,
                        float* __restrict__ out) {
    const int bh = blockIdx.x;
    const int d  = threadIdx.x;
    float l = 0.f, o = 0.f;
    #pragma unroll 8
    for (int s = 0; s < NSP; ++s) {
        l += pl[(size_t)bh * NSP + s];
        o += po[((size_t)bh * NSP + s) * DD + d];
    }
    out[(size_t)bh * DD + d] = o / l;
}

// ---------------------------------------------------------------------------
extern "C" void kernel_launch(void* const* d_in, const int* in_sizes, int n_in,
                              void* d_out, int out_size, void* d_ws, size_t ws_size,
                              hipStream_t stream) {
    const float* q    = (const float*)d_in[0];
    const float* knew = (const float*)d_in[1];
    const float* vnew = (const float*)d_in[2];
    const float* kc   = (const float*)d_in[3];
    const float* vc   = (const float*)d_in[4];
    const int*   bidx = (const int*)d_in[5];
    const float* mask = (const float*)d_in[6];
    const int*   offp = (const int*)d_in[7];

    char* ws = (char*)d_ws;
    int*                trace_tb = (int*)(ws);                          // 131072
    unsigned long long* slot4    = (unsigned long long*)(ws + 131072);  // 16384
    int*                rowstart = (int*)(ws + 147456);                 // 8192
    int*                rows_tu  = (int*)(ws + 155648);                 // 196608
    int*                ts_g     = (int*)(ws + 352256);                 // 512
    int*                ucnt_g   = (int*)(ws + 352768);                 // 512
    float*              pl       = (float*)(ws + 353280);               // 49152
    float*              po       = (float*)(ws + 402432);               // 6291456

    hipLaunchKernelGGL(trace_kernel, dim3(1), dim3(1024), 0, stream,
                       bidx, offp, trace_tb, slot4, rowstart, rows_tu,
                       ts_g, ucnt_g);
    hipLaunchKernelGGL(attn_split_kernel, dim3(HH * NSP), dim3(256), 0, stream,
                       q, knew, vnew, kc, vc, mask,
                       slot4, rowstart, rows_tu, ts_g, ucnt_g, offp,
                       pl, po);
    hipLaunchKernelGGL(attn_reduce_kernel, dim3(BEAMS * HH), dim3(128), 0, stream,
                       pl, po, (float*)d_out);
}